// Round 4
// baseline (252.921 us; speedup 1.0000x reference)
//
#include <hip/hip_runtime.h>
#include <hip/hip_bf16.h>

#define T_ 512

using sh8 = __attribute__((ext_vector_type(8))) short;  // 8 bf16
using fx4 = __attribute__((ext_vector_type(4))) float;  // MFMA acc

__device__ __forceinline__ short bf16r(float x) {
  union { float f; unsigned u; } v; v.f = x;
  unsigned u = v.u;
  u += 0x7fffu + ((u >> 16) & 1u);   // RNE
  return (short)(u >> 16);
}
__device__ __forceinline__ float b2f(short s) {
  union { float f; unsigned u; } v; v.u = ((unsigned)(unsigned short)s) << 16;
  return v.f;
}
__device__ __forceinline__ fx4 mfma_bf16(sh8 a, sh8 b, fx4 c) {
  return __builtin_amdgcn_mfma_f32_16x16x32_bf16(a, b, c, 0, 0, 0);
}

// ---------------------------------------------------------------------------
// k_prep: weights f32->bf16; permuted gamma/beta tables.
__global__ __launch_bounds__(256) void k_prep(
    const float* __restrict__ qw, const float* __restrict__ pw,
    const float* __restrict__ gamma, const float* __restrict__ beta,
    short* __restrict__ qwb, short* __restrict__ pwb,
    float* __restrict__ gq, float* __restrict__ bq,
    float* __restrict__ gv, float* __restrict__ bv)
{
  const int i = blockIdx.x * 256 + threadIdx.x;
  if (i < 49152) qwb[i] = bf16r(qw[i]);
  if (i < 16384) pwb[i] = bf16r(pw[i]);
  if (i < 16384) {
    const int sh = i >> 10, dp = i & 1023;
    const int sect = sh >> 3, h = sh & 7;
    const int gi = (h * 48 + sect * 16 + (dp & 15)) * 64 + (dp >> 4);
    gq[i] = gamma[gi]; bq[i] = beta[gi];
  }
  if (i < 8192) {
    const int h = i >> 10, d = i & 1023;
    const int gi = (h * 48 + 32 + (d >> 6)) * 64 + (d & 63);
    gv[i] = gamma[gi]; bv[i] = beta[gi];
  }
}

// ---------------------------------------------------------------------------
// k_xt: x f32 [b][c][f][t] -> Xb bf16 [(b*64+f)*16 + c/8][t][c%8]
//       (16B chunk = one lane's MFMA B-fragment k-slice). Fully vectorized
//       global on both sides; LDS transpose with 2-way (free) conflicts.
__global__ __launch_bounds__(256) void k_xt(const float* __restrict__ x,
                                            short* __restrict__ Xb)
{
  const int bid = blockIdx.x;
  const int b = bid >> 8, f = (bid >> 2) & 63, tt = bid & 3;
  const int tid = threadIdx.x;

  __shared__ short Xraw[128 * 128];   // [c][tl], 256B pitch, swz ((c&7)<<4)

  // stage1: coalesced float4 reads along t; 8B LDS writes
  {
    const int tq = (tid & 31) * 4, c0 = tid >> 5;   // c0 in 0..7
    const float* xp = x + (((size_t)(b * 128 + c0) * 64 + f) * 512) + tt * 128 + tq;
    #pragma unroll
    for (int p = 0; p < 16; ++p) {
      const int c = c0 + p * 8;
      const float4 fv = *(const float4*)xp;
      xp += 262144;   // +8 c rows
      short4 o;
      o.x = bf16r(fv.x); o.y = bf16r(fv.y); o.z = bf16r(fv.z); o.w = bf16r(fv.w);
      *(short4*)((char*)Xraw + c * 256 + ((2 * tq) ^ ((c & 7) << 4))) = o;
    }
  }
  __syncthreads();

  // stage2: gather 8 consecutive c at fixed t (2B reads, 2-way = free),
  //         write 16B chunks coalesced along t.
  short* xb = Xb + (size_t)((b * 64 + f) * 16) * 4096;   // + (c8*512 + t)*8
  #pragma unroll
  for (int it = 0; it < 8; ++it) {
    const int chunk = tid + it * 256;          // 0..2047
    const int c8 = chunk >> 7, tl = chunk & 127;
    sh8 o;
    #pragma unroll
    for (int e = 0; e < 8; ++e)
      o[e] = *((const short*)((const char*)Xraw + (c8 * 8 + e) * 256 + ((2 * tl) ^ (e << 4))));
    *(sh8*)(xb + ((size_t)c8 * 512 + tt * 128 + tl) * 8) = o;
  }
}

// ---------------------------------------------------------------------------
// kA: per (b, f, tt): Y[384,128] = W @ X; B-frags straight from Xb (L2-hot,
//     8 waves share the 32KB tile). bias+PReLU; column partials -> Pstat;
//     pre-norm bf16 -> Qp/Kp [bh][t][d'=f*16+cl], Vt [bh][d][t].
__global__ __launch_bounds__(512) void kA_qkv(
    const short* __restrict__ Xb, const short* __restrict__ wb,
    const float* __restrict__ bias, const float* __restrict__ alphap,
    short* __restrict__ Qp, short* __restrict__ Kp, short* __restrict__ Vt,
    float* __restrict__ Pstat)
{
  const int bid = blockIdx.x;
  const int b = bid >> 8, f = (bid >> 2) & 63, tt = bid & 3;
  const int tid = threadIdx.x, lane = tid & 63, w = tid >> 6;

  __shared__ float psum[2048];

  const float alpha = alphap[0];
  fx4 acc[3][8];
  #pragma unroll
  for (int mi = 0; mi < 3; ++mi)
    #pragma unroll
    for (int ni = 0; ni < 8; ++ni) acc[mi][ni] = fx4{0.f, 0.f, 0.f, 0.f};

  const short* xb = Xb + (size_t)((b * 64 + f) * 16) * 4096;

  // wave w = head h; mi = sect (q,k,v). K=128 over c, 4 steps.
  #pragma unroll
  for (int ks = 0; ks < 4; ++ks) {
    sh8 a[3];
    #pragma unroll
    for (int mi = 0; mi < 3; ++mi) {
      const int o = w * 48 + mi * 16 + (lane & 15);
      a[mi] = *(const sh8*)(wb + o * 128 + ks * 32 + (lane >> 4) * 8);
    }
    #pragma unroll
    for (int ni = 0; ni < 8; ++ni) {
      const sh8 bf = *(const sh8*)(xb + ((size_t)(ks * 4 + (lane >> 4)) * 512 +
                                         tt * 128 + ni * 16 + (lane & 15)) * 8);
      #pragma unroll
      for (int mi = 0; mi < 3; ++mi)
        acc[mi][ni] = mfma_bf16(a[mi], bf, acc[mi][ni]);
    }
  }

  // bias + PReLU + per-column (t) partial sums
  float s0[8], s1[8];
  #pragma unroll
  for (int ni = 0; ni < 8; ++ni) { s0[ni] = 0.f; s1[ni] = 0.f; }
  #pragma unroll
  for (int mi = 0; mi < 3; ++mi)
    #pragma unroll
    for (int r = 0; r < 4; ++r) {
      const int o = w * 48 + mi * 16 + (lane >> 4) * 4 + r;
      const float bo = bias[o];
      #pragma unroll
      for (int ni = 0; ni < 8; ++ni) {
        float v = acc[mi][ni][r] + bo;
        v = (v >= 0.f) ? v : alpha * v;
        acc[mi][ni][r] = v;
        s0[ni] += v; s1[ni] += v * v;
      }
    }
  #pragma unroll
  for (int ni = 0; ni < 8; ++ni) {
    float a0 = s0[ni], a1 = s1[ni];
    a0 += __shfl_down(a0, 32); a1 += __shfl_down(a1, 32);
    a0 += __shfl_down(a0, 16); a1 += __shfl_down(a1, 16);
    if (lane < 16) {
      psum[((w * 8 + ni) * 16 + lane) * 2 + 0] = a0;
      psum[((w * 8 + ni) * 16 + lane) * 2 + 1] = a1;
    }
  }
  __syncthreads();
  if (tid < 256) {
    const int col = tid & 127, s = tid >> 7;
    const int ni = col >> 4, l = col & 15;
    float a0 = 0.f;
    #pragma unroll
    for (int ww = 0; ww < 8; ++ww) a0 += psum[((ww * 8 + ni) * 16 + l) * 2 + s];
    Pstat[(size_t)s * 131072 + (size_t)b * 32768 + (size_t)f * 512 + tt * 128 + col] = a0;
  }

  // stores: Qp/Kp [bh][t][d'=f*16+cl] packed uint2; Vt [d][t] 32B runs
  const int bh = b * 8 + w;
  #pragma unroll
  for (int mi = 0; mi < 2; ++mi) {
    short* dst = mi ? Kp : Qp;
    #pragma unroll
    for (int ni = 0; ni < 8; ++ni) {
      const int t = tt * 128 + ni * 16 + (lane & 15);
      const unsigned lo = (unsigned)(unsigned short)bf16r(acc[mi][ni][0]) |
                          ((unsigned)(unsigned short)bf16r(acc[mi][ni][1]) << 16);
      const unsigned hi = (unsigned)(unsigned short)bf16r(acc[mi][ni][2]) |
                          ((unsigned)(unsigned short)bf16r(acc[mi][ni][3]) << 16);
      uint2 pk; pk.x = lo; pk.y = hi;
      *(uint2*)(dst + ((size_t)bh * 512 + t) * 1024 + f * 16 + (lane >> 4) * 4) = pk;
    }
  }
  #pragma unroll
  for (int ni = 0; ni < 8; ++ni)
    #pragma unroll
    for (int r = 0; r < 4; ++r) {
      const int cl = (lane >> 4) * 4 + r;
      Vt[((size_t)bh * 1024 + cl * 64 + f) * 512 + tt * 128 + ni * 16 + (lane & 15)] =
          bf16r(acc[2][ni][r]);
    }
}

// ---------------------------------------------------------------------------
// k_stats: reduce Pstat over f -> MuRs[b][t] = {mu, rstd}
__global__ __launch_bounds__(256) void k_stats(const float* __restrict__ Pstat,
                                               float* __restrict__ MuRs)
{
  const int idx = blockIdx.x * 256 + threadIdx.x;   // grid 8 -> 2048
  const int b = idx >> 9, t = idx & 511;
  float s0 = 0.f, s1 = 0.f;
  for (int f = 0; f < 64; ++f) {
    s0 += Pstat[((size_t)b * 64 + f) * 512 + t];
    s1 += Pstat[131072 + ((size_t)b * 64 + f) * 512 + t];
  }
  const float mu = s0 * (1.f / 24576.f);
  const float var = s1 * (1.f / 24576.f) - mu * mu;
  MuRs[idx * 2] = mu;
  MuRs[idx * 2 + 1] = rsqrtf(var + 1e-5f);
}

// ---------------------------------------------------------------------------
// k_qk: S = (Qn.Kn)/32, lower-tri tiles, BK=128; LN applied on load.
__global__ __launch_bounds__(256) void k_qk(
    const short* __restrict__ Qp, const short* __restrict__ Kp,
    const float* __restrict__ MuRs, const float* __restrict__ gq,
    const float* __restrict__ bq, float* __restrict__ S)
{
  const int bid = blockIdx.x;
  const int bh = bid / 10;
  const int j = bid - bh * 10;
  const int qi = (j >= 6) ? 3 : (j >= 3) ? 2 : (j >= 1) ? 1 : 0;
  const int ki = j - qi * (qi + 1) / 2;
  const int b = bh >> 3, h = bh & 7;
  const int tid = threadIdx.x, lane = tid & 63, w = tid >> 6;
  const int wm = w >> 1, wn = w & 1;

  __shared__ short Qs[128 * 128];   // [t][d'-chunk], 256B pitch, swz
  __shared__ short Ks[128 * 128];
  __shared__ float sQ[256], sK[256];

  if (tid < 128) {
    *(float2*)&sQ[tid * 2] = *(const float2*)(MuRs + ((size_t)b * 512 + qi * 128 + tid) * 2);
    *(float2*)&sK[tid * 2] = *(const float2*)(MuRs + ((size_t)b * 512 + ki * 128 + tid) * 2);
  }
  __syncthreads();

  const int op = tid >> 7;                      // 0: Q, 1: K
  const int rowslot = (tid >> 4) & 7, unit = tid & 15;
  const short* src = op ? (Kp + ((size_t)bh * 512 + ki * 128) * 1024)
                        : (Qp + ((size_t)bh * 512 + qi * 128) * 1024);
  const float* murs = op ? sK : sQ;
  short* dstl = op ? Ks : Qs;
  const float* gqp = gq + (size_t)(op * 8 + h) * 1024;
  const float* bqp = bq + (size_t)(op * 8 + h) * 1024;

  fx4 acc[4][4];
  #pragma unroll
  for (int mi = 0; mi < 4; ++mi)
    #pragma unroll
    for (int ni = 0; ni < 4; ++ni) acc[mi][ni] = fx4{0.f, 0.f, 0.f, 0.f};

  for (int ks = 0; ks < 8; ++ks) {
    float g8[8], b8[8];
    *(float4*)&g8[0] = *(const float4*)(gqp + ks * 128 + unit * 8);
    *(float4*)&g8[4] = *(const float4*)(gqp + ks * 128 + unit * 8 + 4);
    *(float4*)&b8[0] = *(const float4*)(bqp + ks * 128 + unit * 8);
    *(float4*)&b8[4] = *(const float4*)(bqp + ks * 128 + unit * 8 + 4);
    __syncthreads();
    #pragma unroll
    for (int rit = 0; rit < 16; ++rit) {
      const int row = rit * 8 + rowslot;
      const sh8 v = *(const sh8*)(src + (size_t)row * 1024 + ks * 128 + unit * 8);
      const float mu = murs[row * 2], rs = murs[row * 2 + 1];
      sh8 o;
      #pragma unroll
      for (int e = 0; e < 8; ++e)
        o[e] = bf16r((b2f(v[e]) - mu) * rs * g8[e] + b8[e]);
      *(sh8*)((char*)dstl + row * 256 + ((unit * 16) ^ ((row & 7) << 4))) = o;
    }
    __syncthreads();
    #pragma unroll
    for (int ksub = 0; ksub < 4; ++ksub) {
      sh8 a[4], bb[4];
      #pragma unroll
      for (int mi = 0; mi < 4; ++mi) {
        const int t = wm * 64 + mi * 16 + (lane & 15);
        a[mi] = *(const sh8*)((const char*)Qs + t * 256 +
                ((ksub * 64 + (lane >> 4) * 16) ^ ((t & 7) << 4)));
      }
      #pragma unroll
      for (int ni = 0; ni < 4; ++ni) {
        const int t = wn * 64 + ni * 16 + (lane & 15);
        bb[ni] = *(const sh8*)((const char*)Ks + t * 256 +
                 ((ksub * 64 + (lane >> 4) * 16) ^ ((t & 7) << 4)));
      }
      #pragma unroll
      for (int mi = 0; mi < 4; ++mi)
        #pragma unroll
        for (int ni = 0; ni < 4; ++ni)
          acc[mi][ni] = mfma_bf16(a[mi], bb[ni], acc[mi][ni]);
    }
  }

  float* Sg = S + (size_t)bh * 262144;
  const int q0 = qi * 128 + wm * 64, k0 = ki * 128 + wn * 64;
  #pragma unroll
  for (int mi = 0; mi < 4; ++mi)
    #pragma unroll
    for (int ni = 0; ni < 4; ++ni) {
      const int q = q0 + mi * 16 + (lane >> 4) * 4;
      const int kc = k0 + ni * 16 + (lane & 15);
      #pragma unroll
      for (int r = 0; r < 4; ++r)
        Sg[(size_t)(q + r) * 512 + kc] = acc[mi][ni][r] * 0.03125f;
    }
}

// ---------------------------------------------------------------------------
// k_softmax: causal softmax S(f32) -> Pb(bf16), zeros above diagonal.
__global__ __launch_bounds__(256) void k_softmax(const float* __restrict__ S,
                                                 short* __restrict__ Pb)
{
  const int row = blockIdx.x * 4 + (threadIdx.x >> 6);
  const int lane = threadIdx.x & 63;
  const int bh = row >> 9, q = row & 511;
  const float* Sr = S + (size_t)bh * 262144 + (size_t)q * 512;
  short* Pr = Pb + (size_t)bh * 262144 + (size_t)q * 512;
  const int n = q + 1;
  float v[8]; float mx = -1e30f;
  #pragma unroll
  for (int i = 0; i < 8; ++i) {
    const int k = lane + i * 64;
    v[i] = (k < n) ? Sr[k] : -1e30f;
    mx = fmaxf(mx, v[i]);
  }
  #pragma unroll
  for (int off = 32; off > 0; off >>= 1) mx = fmaxf(mx, __shfl_xor(mx, off));
  float sum = 0.f;
  #pragma unroll
  for (int i = 0; i < 8; ++i) {
    const float e = (v[i] > -1e29f) ? __expf(v[i] - mx) : 0.f;
    v[i] = e; sum += e;
  }
  #pragma unroll
  for (int off = 32; off > 0; off >>= 1) sum += __shfl_xor(sum, off);
  const float inv = 1.f / sum;
  #pragma unroll
  for (int i = 0; i < 8; ++i) Pr[lane + i * 64] = bf16r(v[i] * inv);
}

// ---------------------------------------------------------------------------
// k_pv: ctx = P @ Vn (V normalized on load), BK=64; LDS-restage -> Cs.
__global__ __launch_bounds__(256) void k_pv(
    const short* __restrict__ Pb, const short* __restrict__ Vt,
    const float* __restrict__ MuRs, const float* __restrict__ gv,
    const float* __restrict__ bv, short* __restrict__ Cs)
{
  const int bid = blockIdx.x;
  const int bh = bid >> 5, qi = (bid >> 3) & 3, dt = bid & 7;
  const int b = bh >> 3, h = bh & 7;
  const int tid = threadIdx.x, lane = tid & 63, w = tid >> 6;
  const int wm = w >> 1, wn = w & 1;

  __shared__ char smem[32768];
  short* Ps = (short*)smem;                // [128 q][64 k], 128B pitch
  short* Vs = (short*)(smem + 16384);      // [128 d][64 k]
  short* ctile = (short*)smem;             // [128 d][128 q] reuse after loop

  const short* Pg = Pb + ((size_t)bh * 512 + qi * 128) * 512;
  const short* Vg = Vt + ((size_t)bh * 1024 + dt * 128) * 512;
  const float* gvp = gv + (size_t)h * 1024 + dt * 128;
  const float* bvp = bv + (size_t)h * 1024 + dt * 128;
  const float* mrp = MuRs + (size_t)b * 1024;

  const int rowslot = tid >> 3, unit = tid & 7;

  fx4 acc[4][4];
  #pragma unroll
  for (int mi = 0; mi < 4; ++mi)
    #pragma unroll
    for (int ni = 0; ni < 4; ++ni) acc[mi][ni] = fx4{0.f, 0.f, 0.f, 0.f};

  const int nks = (qi + 1) * 2;
  for (int ks = 0; ks < nks; ++ks) {
    float mr[16];   // {mu,rs} for k = ks*64 + unit*8 + e
    *(float4*)&mr[0]  = *(const float4*)(mrp + (ks * 64 + unit * 8) * 2);
    *(float4*)&mr[4]  = *(const float4*)(mrp + (ks * 64 + unit * 8) * 2 + 4);
    *(float4*)&mr[8]  = *(const float4*)(mrp + (ks * 64 + unit * 8) * 2 + 8);
    *(float4*)&mr[12] = *(const float4*)(mrp + (ks * 64 + unit * 8) * 2 + 12);
    __syncthreads();
    #pragma unroll
    for (int rit = 0; rit < 4; ++rit) {
      const int row = rit * 32 + rowslot;
      const sh8 p = *(const sh8*)(Pg + (size_t)row * 512 + ks * 64 + unit * 8);
      *(sh8*)((char*)Ps + row * 128 + ((unit * 16) ^ ((row & 7) << 4))) = p;
      const sh8 vv = *(const sh8*)(Vg + (size_t)row * 512 + ks * 64 + unit * 8);
      const float g = gvp[row], be = bvp[row];
      sh8 o;
      #pragma unroll
      for (int e = 0; e < 8; ++e)
        o[e] = bf16r((b2f(vv[e]) - mr[e * 2]) * mr[e * 2 + 1] * g + be);
      *(sh8*)((char*)Vs + row * 128 + ((unit * 16) ^ ((row & 7) << 4))) = o;
    }
    __syncthreads();
    #pragma unroll
    for (int ksub = 0; ksub < 2; ++ksub) {
      sh8 a[4], bb[4];
      #pragma unroll
      for (int mi = 0; mi < 4; ++mi) {
        const int r2 = wm * 64 + mi * 16 + (lane & 15);
        a[mi] = *(const sh8*)((const char*)Ps + r2 * 128 +
                ((ksub * 64 + (lane >> 4) * 16) ^ ((r2 & 7) << 4)));
      }
      #pragma unroll
      for (int ni = 0; ni < 4; ++ni) {
        const int r2 = wn * 64 + ni * 16 + (lane & 15);
        bb[ni] = *(const sh8*)((const char*)Vs + r2 * 128 +
                 ((ksub * 64 + (lane >> 4) * 16) ^ ((r2 & 7) << 4)));
      }
      #pragma unroll
      for (int mi = 0; mi < 4; ++mi)
        #pragma unroll
        for (int ni = 0; ni < 4; ++ni)
          acc[mi][ni] = mfma_bf16(a[mi], bb[ni], acc[mi][ni]);
    }
  }
  __syncthreads();   // protect Ps/Vs reads before ctile overwrite

  #pragma unroll
  for (int mi = 0; mi < 4; ++mi)
    #pragma unroll
    for (int ni = 0; ni < 4; ++ni) {
      const int ql = wm * 64 + mi * 16 + (lane >> 4) * 4;
      const int dl = wn * 64 + ni * 16 + (lane & 15);
      const int swz = (dl & 7) << 4;
      #pragma unroll
      for (int r = 0; r < 4; ++r)
        ctile[(dl * 256 + ((2 * (ql + r)) ^ swz)) >> 1] = bf16r(acc[mi][ni][r]);
    }
  __syncthreads();

  // scrambled write: c[b][C][t2][f2] in 128B f2-runs
  const int cl_loc = tid >> 7, fq = (tid >> 1) & 63, tg_loc = tid & 1;
  const int C = h * 16 + dt * 2 + cl_loc;
  const int t2 = fq * 8 + qi * 2 + tg_loc;
  const int dl = cl_loc * 64 + fq;
  const int swz = (dl & 7) << 4;
  short* dst = Cs + (((size_t)b * 128 + C) * 512 + t2) * 64;
  #pragma unroll
  for (int jj = 0; jj < 8; ++jj) {
    const sh8 vv = *(const sh8*)((const char*)ctile + dl * 256 + ((tg_loc * 128 + jj * 16) ^ swz));
    *(sh8*)(dst + jj * 8) = vv;
  }
}

// ---------------------------------------------------------------------------
// k_proj: per (b,t2): Y[128,64] = Wp @ C; bias+PReLU+LN; -> Otmp bf16 [b][o][t2][f2]
__global__ __launch_bounds__(512) void k_proj(
    const short* __restrict__ Cs, const short* __restrict__ wb,
    const float* __restrict__ bias, const float* __restrict__ alphap,
    const float* __restrict__ gamma, const float* __restrict__ beta,
    short* __restrict__ Otmpb)
{
  const int bid = blockIdx.x;
  const int b = bid >> 9, t2 = bid & 511;
  const int tid = threadIdx.x, lane = tid & 63, w = tid >> 6;

  __shared__ short Xs[64 * 128];   // [f2][C], 256B pitch, swz
  __shared__ float red[18];

  {
    const int rowslot = tid >> 3, unit = tid & 7;
    #pragma unroll
    for (int rit = 0; rit < 2; ++rit) {
      const int C = rit * 64 + rowslot;
      const sh8 vv = *(const sh8*)(Cs + (((size_t)b * 128 + C) * 512 + t2) * 64 + unit * 8);
      #pragma unroll
      for (int jj = 0; jj < 8; ++jj) {
        const int f2 = unit * 8 + jj;
        *((short*)((char*)Xs + f2 * 256 + ((2 * C) ^ ((f2 & 7) << 4)))) = vv[jj];
      }
    }
  }
  __syncthreads();

  const float alpha = alphap[0];
  fx4 acc[4];
  #pragma unroll
  for (int ni = 0; ni < 4; ++ni) acc[ni] = fx4{0.f, 0.f, 0.f, 0.f};

  #pragma unroll
  for (int ks = 0; ks < 4; ++ks) {
    const int o = w * 16 + (lane & 15);
    const sh8 a = *(const sh8*)(wb + o * 128 + ks * 32 + (lane >> 4) * 8);
    #pragma unroll
    for (int ni = 0; ni < 4; ++ni) {
      const int f2 = ni * 16 + (lane & 15);
      const sh8 bf = *(const sh8*)((const char*)Xs + f2 * 256 +
                     ((ks * 64 + (lane >> 4) * 16) ^ ((f2 & 7) << 4)));
      acc[ni] = mfma_bf16(a, bf, acc[ni]);
    }
  }

  float s0 = 0.f, s1 = 0.f;
  const int ob = w * 16 + (lane >> 4) * 4;
  #pragma unroll
  for (int ni = 0; ni < 4; ++ni)
    #pragma unroll
    for (int r = 0; r < 4; ++r) {
      float v = acc[ni][r] + bias[ob + r];
      v = (v >= 0.f) ? v : alpha * v;
      acc[ni][r] = v;
      s0 += v; s1 += v * v;
    }
  #pragma unroll
  for (int off = 32; off > 0; off >>= 1) { s0 += __shfl_down(s0, off); s1 += __shfl_down(s1, off); }
  if (lane == 0) { red[w * 2] = s0; red[w * 2 + 1] = s1; }
  __syncthreads();
  if (tid == 0) {
    float a0 = 0.f, a1 = 0.f;
    for (int i2 = 0; i2 < 8; ++i2) { a0 += red[2 * i2]; a1 += red[2 * i2 + 1]; }
    const float mu = a0 / 8192.f;
    const float var = a1 / 8192.f - mu * mu;
    red[16] = mu; red[17] = rsqrtf(var + 1e-5f);
  }
  __syncthreads();
  const float mu = red[16], rstd = red[17];

  #pragma unroll
  for (int ni = 0; ni < 4; ++ni) {
    const int f2 = ni * 16 + (lane & 15);
    #pragma unroll
    for (int r = 0; r < 4; ++r) {
      const int o = ob + r;
      const float zz = (acc[ni][r] - mu) * rstd * gamma[o * 64 + f2] + beta[o * 64 + f2];
      Otmpb[(((size_t)b * 128 + o) * 512 + t2) * 64 + f2] = bf16r(zz);
    }
  }
}

// ---------------------------------------------------------------------------
// k_trans: Otmp bf16 [b][o][t2][f2] -> out f32 [b][o][f2][t2]
__global__ __launch_bounds__(256) void k_trans(const short* __restrict__ Otmpb,
                                               float* __restrict__ out)
{
  const int bid = blockIdx.x;
  const int bo = bid >> 3, tt8 = bid & 7;
  const int t20 = tt8 * 64;
  const int tid = threadIdx.x;
  __shared__ float Ltr[64 * 68];   // [f2][t2], pitch 68

  {
    const int t2l = tid >> 2, u = tid & 3;
    const short* srow = Otmpb + ((size_t)bo * 512 + t20 + t2l) * 64 + u * 16;
    const sh8 v0 = *(const sh8*)(srow);
    const sh8 v1 = *(const sh8*)(srow + 8);
    #pragma unroll
    for (int e = 0; e < 8; ++e) {
      Ltr[(u * 16 + e) * 68 + t2l]     = b2f(v0[e]);
      Ltr[(u * 16 + 8 + e) * 68 + t2l] = b2f(v1[e]);
    }
  }
  __syncthreads();
  {
    const int f2 = tid >> 2, u = tid & 3;
    float* dst = out + ((size_t)bo * 64 + f2) * 512 + t20 + u * 16;
    #pragma unroll
    for (int k = 0; k < 4; ++k)
      *(float4*)(dst + k * 4) = *(const float4*)&Ltr[f2 * 68 + u * 16 + k * 4];
  }
}

// ---------------------------------------------------------------------------
extern "C" void kernel_launch(void* const* d_in, const int* in_sizes, int n_in,
                              void* d_out, int out_size, void* d_ws, size_t ws_size,
                              hipStream_t stream) {
  (void)in_sizes; (void)n_in; (void)out_size;
  const float* x          = (const float*)d_in[0];
  const float* qkv_w      = (const float*)d_in[1];
  const float* qkv_b      = (const float*)d_in[2];
  const float* qkv_alpha  = (const float*)d_in[3];
  const float* qkv_gamma  = (const float*)d_in[4];
  const float* qkv_beta   = (const float*)d_in[5];
  const float* proj_w     = (const float*)d_in[6];
  const float* proj_b     = (const float*)d_in[7];
  const float* proj_alpha = (const float*)d_in[8];
  const float* proj_gamma = (const float*)d_in[9];
  const float* proj_beta  = (const float*)d_in[10];
  float* out = (float*)d_out;

  // ws (lifetime-aliased, total 167,903,232 B known safe):
  //  @0       : Qp [kA->k_qk]   ; Cs after k_qk
  //  @33.5M   : Kp [kA->k_qk]   ; Otmpb after k_qk
  //  @67M     : Vt [kA->k_pv]
  //  @100.7M  : Xb [k_xt->kA]   ; S f32 after kA (written by k_qk)
  //  @134.2M  : Pb bf16 [k_softmax->k_pv]
  //  @151M    : MuRs + gq/bq/gv/bv tables
  //  @167.77M : qwb, pwb
  //  Pstat (1MB): stashed in d_out, fully overwritten by k_trans
  char* ws = (char*)d_ws;
  short* Qp   = (short*)(ws + 0);
  short* Kp   = (short*)(ws + 33554432);
  short* Vt   = (short*)(ws + 67108864);
  short* Xb   = (short*)(ws + 100663296);
  float* S    = (float*)(ws + 100663296);
  short* Pb   = (short*)(ws + 134217728);
  float* MuRs = (float*)(ws + 150994944);
  float* gq   = (float*)(ws + 151011328);
  float* bq   = (float*)(ws + 151076864);
  float* gv   = (float*)(ws + 151142400);
  float* bv   = (float*)(ws + 151175168);
  short* Cs    = (short*)(ws + 0);
  short* Otmpb = (short*)(ws + 33554432);
  short* qwb  = (short*)(ws + 167772160);
  short* pwb  = (short*)(ws + 167870464);
  float* Pstat = (float*)d_out;
  if (ws_size < 167903232u) return;

  k_prep<<<192, 256, 0, stream>>>(qkv_w, proj_w, qkv_gamma, qkv_beta,
                                  qwb, pwb, gq, bq, gv, bv);
  k_xt<<<1024, 256, 0, stream>>>(x, Xb);
  kA_qkv<<<1024, 512, 0, stream>>>(Xb, qwb, qkv_b, qkv_alpha, Qp, Kp, Vt, Pstat);
  k_stats<<<8, 256, 0, stream>>>(Pstat, MuRs);
  k_qk<<<320, 256, 0, stream>>>(Qp, Kp, MuRs, gq, bq, S);
  k_softmax<<<4096, 256, 0, stream>>>(S, Pb);
  k_pv<<<1024, 256, 0, stream>>>(Pb, Vt, MuRs, gv, bv, Cs);
  k_proj<<<2048, 512, 0, stream>>>(Cs, pwb, proj_b, proj_alpha, proj_gamma, proj_beta, Otmpb);
  k_trans<<<4096, 256, 0, stream>>>(Otmpb, out);
}